// Round 1
// baseline (384.358 us; speedup 1.0000x reference)
//
#include <hip/hip_runtime.h>
#include <math.h>

// CORM attention, MI355X / gfx950.
// B=1, Q=KV=2048, H=32, D=128, fp32 in/out.
// Kernel 1: flash attention (cheap bf16 MFMA) -> out + T[h][q] = logsumexp(row) - log(q+1)
// Kernel 2: corm score via accurate bf16x3 scores compared against T (log-domain).

#define HN   32
#define DH   128
#define SEQ  2048
#define QB   64
#define KB   64
#define SCALEF 0.08838834764831843f  // 1/sqrt(128)

typedef __attribute__((ext_vector_type(4))) float f4;
typedef __attribute__((ext_vector_type(8))) short s8;

__device__ __forceinline__ short f2bf(float x) {
  union { float f; unsigned u; } a; a.f = x;
  unsigned r = a.u + 0x7FFFu + ((a.u >> 16) & 1u);  // RNE
  return (short)(r >> 16);
}
__device__ __forceinline__ float bf2f(short h) {
  union { unsigned u; float f; } a;
  a.u = ((unsigned)(unsigned short)h) << 16;
  return a.f;
}
// swizzled short-index in a row-major [R][Cshort] bf16 tile: byte ^= (row&7)<<4
__device__ __forceinline__ int swz(int row, int colShort, int Cshort) {
  int byte = (colShort * 2) ^ ((row & 7) << 4);
  return row * Cshort + (byte >> 1);
}

// ---------------------------------------------------------------- kernel 1
__global__ __launch_bounds__(256, 2) void flash_fwd(
    const float* __restrict__ gQ, const float* __restrict__ gK,
    const float* __restrict__ gV, float* __restrict__ gO,
    float* __restrict__ gT)
{
  __shared__ short Qs[QB * DH];      // 16 KB, swizzled row-major [q][d]
  __shared__ short Ks[KB * DH];      // 16 KB, swizzled row-major [kv][d]
  __shared__ short Vt[DH * KB];      // 16 KB, swizzled row-major [d][kv] (transposed)
  __shared__ short Ps[4][16 * KB];   // 8 KB, per-wave P tile [q16][kv64]

  const int qblk = blockIdx.x, h = blockIdx.y;
  const int qb = qblk * QB;
  const int tid = threadIdx.x;
  const int wv = tid >> 6, ln = tid & 63, l15 = ln & 15, l4 = ln >> 4;

  // ---- stage Q block (bf16 hi), swizzled
  for (int i = 0; i < 4; ++i) {
    int c = tid + 256 * i;                 // 1024 chunks of 8 elems
    int r = c >> 4, c0 = (c & 15) * 8;
    const float* src = gQ + ((size_t)(qb + r) * HN + h) * DH + c0;
    f4 a = *(const f4*)src, b = *(const f4*)(src + 4);
    s8 o;
    o[0]=f2bf(a[0]); o[1]=f2bf(a[1]); o[2]=f2bf(a[2]); o[3]=f2bf(a[3]);
    o[4]=f2bf(b[0]); o[5]=f2bf(b[1]); o[6]=f2bf(b[2]); o[7]=f2bf(b[3]);
    *(s8*)&Qs[swz(r, c0, DH)] = o;
  }
  __syncthreads();

  // Q A-frags for this wave's 16 rows, kept in regs for the whole kv loop
  s8 qf[4];
#pragma unroll
  for (int dt = 0; dt < 4; ++dt)
    qf[dt] = *(const s8*)&Qs[swz(wv * 16 + l15, dt * 32 + l4 * 8, DH)];

  f4 oacc[8];
#pragma unroll
  for (int i = 0; i < 8; ++i) { oacc[i][0]=0.f; oacc[i][1]=0.f; oacc[i][2]=0.f; oacc[i][3]=0.f; }
  float m_[4] = {-INFINITY, -INFINITY, -INFINITY, -INFINITY};
  float l_[4] = {0.f, 0.f, 0.f, 0.f};

  const int ntile = qblk + 1;
  for (int t = 0; t < ntile; ++t) {
    const int kv0 = t * KB;
    __syncthreads();
    // ---- stage K rows (bf16 hi), swizzled
    for (int i = 0; i < 4; ++i) {
      int c = tid + 256 * i;
      int r = c >> 4, c0 = (c & 15) * 8;
      const float* src = gK + ((size_t)(kv0 + r) * HN + h) * DH + c0;
      f4 a = *(const f4*)src, b = *(const f4*)(src + 4);
      s8 o;
      o[0]=f2bf(a[0]); o[1]=f2bf(a[1]); o[2]=f2bf(a[2]); o[3]=f2bf(a[3]);
      o[4]=f2bf(b[0]); o[5]=f2bf(b[1]); o[6]=f2bf(b[2]); o[7]=f2bf(b[3]);
      *(s8*)&Ks[swz(r, c0, DH)] = o;
    }
    // ---- stage V transposed [d][kv], packed pair writes
    {
      int kv = (tid & 31) * 2, d0 = (tid >> 5) * 16;
      const float* v0 = gV + ((size_t)(kv0 + kv) * HN + h) * DH + d0;
      const float* v1 = v0 + HN * DH;
      for (int dd = 0; dd < 16; dd += 4) {
        f4 x = *(const f4*)(v0 + dd), y = *(const f4*)(v1 + dd);
#pragma unroll
        for (int e = 0; e < 4; ++e) {
          int d = d0 + dd + e;
          unsigned pk = (unsigned)(unsigned short)f2bf(x[e]) |
                        ((unsigned)(unsigned short)f2bf(y[e]) << 16);
          *(unsigned*)((char*)Vt + (d * 128 + ((kv * 2) ^ ((d & 7) << 4)))) = pk;
        }
      }
    }
    __syncthreads();

    // ---- S = Q K^T  (D layout: col kv = l15 + 16n, row q = 4*l4 + j)
    f4 sacc[4];
#pragma unroll
    for (int n = 0; n < 4; ++n) { sacc[n][0]=0.f; sacc[n][1]=0.f; sacc[n][2]=0.f; sacc[n][3]=0.f; }
#pragma unroll
    for (int n = 0; n < 4; ++n)
#pragma unroll
      for (int dt = 0; dt < 4; ++dt) {
        s8 kf = *(const s8*)&Ks[swz(n * 16 + l15, dt * 32 + l4 * 8, DH)];
        sacc[n] = __builtin_amdgcn_mfma_f32_16x16x32_bf16(qf[dt], kf, sacc[n], 0, 0, 0);
      }

    // ---- mask + online softmax (rows 4*l4+j, spread over 16 lanes)
    float pj[4][4];  // [n][j]
    float rm[4] = {-INFINITY, -INFINITY, -INFINITY, -INFINITY};
#pragma unroll
    for (int n = 0; n < 4; ++n) {
      int kvcol = kv0 + n * 16 + l15;
#pragma unroll
      for (int j = 0; j < 4; ++j) {
        int qg = qb + wv * 16 + 4 * l4 + j;
        float s = sacc[n][j] * SCALEF;
        if (kvcol > qg) s = -INFINITY;
        pj[n][j] = s;
        rm[j] = fmaxf(rm[j], s);
      }
    }
#pragma unroll
    for (int j = 0; j < 4; ++j) {
      rm[j] = fmaxf(rm[j], __shfl_xor(rm[j], 1, 16));
      rm[j] = fmaxf(rm[j], __shfl_xor(rm[j], 2, 16));
      rm[j] = fmaxf(rm[j], __shfl_xor(rm[j], 4, 16));
      rm[j] = fmaxf(rm[j], __shfl_xor(rm[j], 8, 16));
    }
    float alpha[4], rs[4];
#pragma unroll
    for (int j = 0; j < 4; ++j) {
      float mn = fmaxf(m_[j], rm[j]);     // finite after tile 0 (kv=0 <= q always)
      alpha[j] = __expf(m_[j] - mn);      // -inf - finite = -inf -> 0, never NaN
      m_[j] = mn;
      float s0 = 0.f;
#pragma unroll
      for (int n = 0; n < 4; ++n) {
        float p = __expf(pj[n][j] - mn);  // masked -inf -> 0
        pj[n][j] = p;
        s0 += p;
      }
      rs[j] = s0;
    }
#pragma unroll
    for (int j = 0; j < 4; ++j) {
      rs[j] += __shfl_xor(rs[j], 1, 16);
      rs[j] += __shfl_xor(rs[j], 2, 16);
      rs[j] += __shfl_xor(rs[j], 4, 16);
      rs[j] += __shfl_xor(rs[j], 8, 16);
      l_[j] = l_[j] * alpha[j] + rs[j];
    }
#pragma unroll
    for (int i = 0; i < 8; ++i)
#pragma unroll
      for (int j = 0; j < 4; ++j) oacc[i][j] *= alpha[j];

    // ---- P (bf16) to per-wave LDS tile, D-layout scatter writes
    short* pw = Ps[wv];
#pragma unroll
    for (int n = 0; n < 4; ++n)
#pragma unroll
      for (int j = 0; j < 4; ++j) {
        int row = 4 * l4 + j, col = n * 16 + l15;
        pw[swz(row, col, KB)] = f2bf(pj[n][j]);
      }
    __syncthreads();

    // ---- PV: out[16q][128d] += P[16q][64kv] * V[64kv][128d]
    s8 pa0 = *(const s8*)&pw[swz(l15, l4 * 8, KB)];
    s8 pa1 = *(const s8*)&pw[swz(l15, 32 + l4 * 8, KB)];
#pragma unroll
    for (int ds = 0; ds < 8; ++ds) {
      s8 vb0 = *(const s8*)&Vt[swz(ds * 16 + l15, l4 * 8, KB)];
      oacc[ds] = __builtin_amdgcn_mfma_f32_16x16x32_bf16(pa0, vb0, oacc[ds], 0, 0, 0);
      s8 vb1 = *(const s8*)&Vt[swz(ds * 16 + l15, 32 + l4 * 8, KB)];
      oacc[ds] = __builtin_amdgcn_mfma_f32_16x16x32_bf16(pa1, vb1, oacc[ds], 0, 0, 0);
    }
  }

  // ---- epilogue: normalize + write out, write T = m + log(l) - log(q+1)
#pragma unroll
  for (int j = 0; j < 4; ++j) {
    int qg = qb + wv * 16 + 4 * l4 + j;
    float inv = 1.0f / l_[j];
    float* orow = gO + ((size_t)qg * HN + h) * DH;
#pragma unroll
    for (int ds = 0; ds < 8; ++ds)
      orow[ds * 16 + l15] = oacc[ds][j] * inv;
    if (l15 == 0)
      gT[h * SEQ + qg] = m_[j] + logf(l_[j]) - logf((float)(qg + 1));
  }
}

// ---------------------------------------------------------------- kernel 2
// corm[h][kv] = OR_{q>=kv} ( s_accurate[q][kv] >= T[q] ), s via bf16x3 MFMA.
__global__ __launch_bounds__(256, 2) void corm_fwd(
    const float* __restrict__ gQ, const float* __restrict__ gK,
    const float* __restrict__ gT, float* __restrict__ gC)
{
  __shared__ short Qh[QB * DH];   // 16 KB
  __shared__ short Ql[QB * DH];   // 16 KB
  __shared__ float Tt[QB];

  const int kvblk = blockIdx.x, h = blockIdx.y;
  const int kvb = kvblk * KB;
  const int tid = threadIdx.x;
  const int wv = tid >> 6, ln = tid & 63, l15 = ln & 15, l4 = ln >> 4;

  // this wave's 16 K rows as hi/lo A-frags, registers for the whole q loop
  s8 khi[4], klo[4];
  {
    const float* krow = gK + ((size_t)(kvb + wv * 16 + l15) * HN + h) * DH;
#pragma unroll
    for (int dt = 0; dt < 4; ++dt) {
      f4 a = *(const f4*)(krow + dt * 32 + l4 * 8);
      f4 b = *(const f4*)(krow + dt * 32 + l4 * 8 + 4);
#pragma unroll
      for (int e = 0; e < 4; ++e) {
        short hi = f2bf(a[e]);
        khi[dt][e] = hi; klo[dt][e] = f2bf(a[e] - bf2f(hi));
        short hi2 = f2bf(b[e]);
        khi[dt][4 + e] = hi2; klo[dt][4 + e] = f2bf(b[e] - bf2f(hi2));
      }
    }
  }

  int fired[4] = {0, 0, 0, 0};
  const int kvrow_mine = kvb + wv * 16 + 4 * l4;  // + j

  for (int t = kvblk; t < SEQ / QB; ++t) {
    __syncthreads();
    // ---- stage Q tile hi/lo, swizzled
    for (int i = 0; i < 4; ++i) {
      int c = tid + 256 * i;
      int r = c >> 4, c0 = (c & 15) * 8;
      const float* src = gQ + ((size_t)(t * QB + r) * HN + h) * DH + c0;
      f4 a = *(const f4*)src, b = *(const f4*)(src + 4);
      s8 oh, ol;
#pragma unroll
      for (int e = 0; e < 4; ++e) {
        short hi = f2bf(a[e]);
        oh[e] = hi; ol[e] = f2bf(a[e] - bf2f(hi));
        short hi2 = f2bf(b[e]);
        oh[4 + e] = hi2; ol[4 + e] = f2bf(b[e] - bf2f(hi2));
      }
      *(s8*)&Qh[swz(r, c0, DH)] = oh;
      *(s8*)&Ql[swz(r, c0, DH)] = ol;
    }
    if (tid < QB) Tt[tid] = gT[h * SEQ + t * QB + tid];
    __syncthreads();

    // ---- S^T tiles: D[kv16][q16] per n, bf16x3 accumulate
#pragma unroll
    for (int n = 0; n < 4; ++n) {
      f4 acc; acc[0]=0.f; acc[1]=0.f; acc[2]=0.f; acc[3]=0.f;
#pragma unroll
      for (int dt = 0; dt < 4; ++dt) {
        s8 qhb = *(const s8*)&Qh[swz(n * 16 + l15, dt * 32 + l4 * 8, DH)];
        s8 qlb = *(const s8*)&Ql[swz(n * 16 + l15, dt * 32 + l4 * 8, DH)];
        acc = __builtin_amdgcn_mfma_f32_16x16x32_bf16(khi[dt], qhb, acc, 0, 0, 0);
        acc = __builtin_amdgcn_mfma_f32_16x16x32_bf16(khi[dt], qlb, acc, 0, 0, 0);
        acc = __builtin_amdgcn_mfma_f32_16x16x32_bf16(klo[dt], qhb, acc, 0, 0, 0);
      }
      int qg = t * QB + n * 16 + l15;
      float Tq = Tt[n * 16 + l15];
#pragma unroll
      for (int j = 0; j < 4; ++j) {
        int kvr = kvrow_mine + j;
        if (qg >= kvr && acc[j] * SCALEF >= Tq) fired[j] = 1;
      }
    }
  }

#pragma unroll
  for (int j = 0; j < 4; ++j) {
    fired[j] |= __shfl_xor(fired[j], 1, 16);
    fired[j] |= __shfl_xor(fired[j], 2, 16);
    fired[j] |= __shfl_xor(fired[j], 4, 16);
    fired[j] |= __shfl_xor(fired[j], 8, 16);
  }
  if (l15 == 0) {
#pragma unroll
    for (int j = 0; j < 4; ++j)
      gC[h * SEQ + kvrow_mine + j] = fired[j] ? 1.0f : 0.0f;
  }
}

// ---------------------------------------------------------------- launcher
extern "C" void kernel_launch(void* const* d_in, const int* in_sizes, int n_in,
                              void* d_out, int out_size, void* d_ws, size_t ws_size,
                              hipStream_t stream) {
  const float* q = (const float*)d_in[0];
  const float* k = (const float*)d_in[1];
  const float* v = (const float*)d_in[2];
  // d_in[3] = corm_mask: row i is exactly 1/(i+1); folded analytically into T.
  float* out  = (float*)d_out;
  float* corm = out + (size_t)SEQ * HN * DH;
  float* T    = (float*)d_ws;  // HN*SEQ floats = 256 KB

  dim3 blk(256);
  flash_fwd<<<dim3(SEQ / QB, HN), blk, 0, stream>>>(q, k, v, out, T);
  corm_fwd<<<dim3(SEQ / KB, HN), blk, 0, stream>>>(q, k, T, corm);
}

// Round 2
// 308.519 us; speedup vs baseline: 1.2458x; 1.2458x over previous
//
#include <hip/hip_runtime.h>
#include <math.h>

// CORM attention v2, MI355X / gfx950.
// prep: fp32 -> bf16 tile images (exact swizzled LDS layout) for Q(hi,lo), K(hi), V^T
// flash: double-buffered global_load_lds pipeline, counted vmcnt -> out + T=lse-log(q+1)
// corm : bf16x3 scores vs T, same pipeline on Q(hi,lo) tiles.
// ws requirement: 4 * 16MiB + 256KiB ~= 64.3 MiB

#define HN   32
#define DH   128
#define SEQ  2048
#define NBLK 32            // SEQ / 64
#define QB   64
#define KB   64
#define TILE_SHORTS 8192   // 64 * 128
#define SCALEF 0.08838834764831843f  // 1/sqrt(128)

typedef __attribute__((ext_vector_type(4))) float f4;
typedef __attribute__((ext_vector_type(8))) short s8;

typedef __attribute__((address_space(3))) unsigned lds_u32;
typedef const __attribute__((address_space(1))) unsigned glob_u32;

__device__ __forceinline__ short f2bf(float x) {
  union { float f; unsigned u; } a; a.f = x;
  unsigned r = a.u + 0x7FFFu + ((a.u >> 16) & 1u);  // RNE
  return (short)(r >> 16);
}
__device__ __forceinline__ float bf2f(short h) {
  union { unsigned u; float f; } a;
  a.u = ((unsigned)(unsigned short)h) << 16;
  return a.f;
}
// swizzled short-index in a row-major [R][Cshort] bf16 tile: byte ^= (row&7)<<4
__device__ __forceinline__ int swz(int row, int colShort, int Cshort) {
  int byte = (colShort * 2) ^ ((row & 7) << 4);
  return row * Cshort + (byte >> 1);
}

// one wave stages its 4KB quarter of a 16KB tile image: 4 x global_load_lds(16B)
__device__ __forceinline__ void stage_wave(const char* gsrc, char* ldst, int wv, int ln) {
#pragma unroll
  for (int i = 0; i < 4; ++i) {
    __builtin_amdgcn_global_load_lds(
        (glob_u32*)(gsrc + wv * 4096 + i * 1024 + ln * 16),
        (lds_u32*)(ldst + wv * 4096 + i * 1024), 16, 0, 0);
  }
}

// ---------------------------------------------------------------- prep
__global__ __launch_bounds__(256) void prep_qkv(
    const float* __restrict__ gQ, const float* __restrict__ gK,
    const float* __restrict__ gV, short* __restrict__ oQh,
    short* __restrict__ oQl, short* __restrict__ oKs, short* __restrict__ oVt)
{
  __shared__ short Vs[64][136];  // padded: 272B row stride
  const int blk = blockIdx.x, h = blockIdx.y, tid = threadIdx.x;
  const size_t toff = ((size_t)h * NBLK + blk) * TILE_SHORTS;

#pragma unroll
  for (int i = 0; i < 4; ++i) {
    int c = tid + 256 * i, r = c >> 4, c0 = (c & 15) * 8;
    size_t rowoff = ((size_t)(blk * 64 + r) * HN + h) * DH + c0;
    {  // Q hi/lo
      f4 a = *(const f4*)(gQ + rowoff), b = *(const f4*)(gQ + rowoff + 4);
      s8 oh, ol;
#pragma unroll
      for (int e = 0; e < 4; ++e) {
        short hi = f2bf(a[e]); oh[e] = hi; ol[e] = f2bf(a[e] - bf2f(hi));
        short h2 = f2bf(b[e]); oh[4+e] = h2; ol[4+e] = f2bf(b[e] - bf2f(h2));
      }
      *(s8*)&oQh[toff + swz(r, c0, DH)] = oh;
      *(s8*)&oQl[toff + swz(r, c0, DH)] = ol;
    }
    {  // K hi
      f4 a = *(const f4*)(gK + rowoff), b = *(const f4*)(gK + rowoff + 4);
      s8 o;
#pragma unroll
      for (int e = 0; e < 4; ++e) { o[e] = f2bf(a[e]); o[4+e] = f2bf(b[e]); }
      *(s8*)&oKs[toff + swz(r, c0, DH)] = o;
    }
    {  // V -> LDS (linear, padded)
      f4 a = *(const f4*)(gV + rowoff), b = *(const f4*)(gV + rowoff + 4);
      s8 o;
#pragma unroll
      for (int e = 0; e < 4; ++e) { o[e] = f2bf(a[e]); o[4+e] = f2bf(b[e]); }
      *(s8*)&Vs[r][c0] = o;
    }
  }
  __syncthreads();
  // V^T tile image: row d (128 rows) of 64 kv shorts, swizzled
#pragma unroll
  for (int i = 0; i < 4; ++i) {
    int c = tid + 256 * i, d = c >> 3, k0 = (c & 7) * 8;
    s8 o;
#pragma unroll
    for (int j = 0; j < 8; ++j) o[j] = Vs[k0 + j][d];
    *(s8*)&oVt[toff + swz(d, k0, KB)] = o;
  }
}

// ---------------------------------------------------------------- kernel 1
__global__ __launch_bounds__(256, 2) void flash_fwd(
    const short* __restrict__ gQh, const short* __restrict__ gKs,
    const short* __restrict__ gVt, float* __restrict__ gO,
    float* __restrict__ gT)
{
  __shared__ short Ks[2][TILE_SHORTS];   // 32 KB
  __shared__ short Vt[2][TILE_SHORTS];   // 32 KB
  __shared__ short Ps[4][16 * KB];       // 8 KB

  const int qblk = (gridDim.x - 1) - blockIdx.x, h = blockIdx.y;  // heavy first
  const int qb = qblk * QB;
  const int tid = threadIdx.x;
  const int wv = tid >> 6, ln = tid & 63, l15 = ln & 15, l4 = ln >> 4;

  const size_t hbase = (size_t)h * NBLK * TILE_SHORTS;
  const short* qtile = gQh + hbase + (size_t)qblk * TILE_SHORTS;

  s8 qf[4];
#pragma unroll
  for (int dt = 0; dt < 4; ++dt)
    qf[dt] = *(const s8*)&qtile[swz(wv * 16 + l15, dt * 32 + l4 * 8, DH)];

  f4 oacc[8];
#pragma unroll
  for (int i = 0; i < 8; ++i) { oacc[i][0]=0.f; oacc[i][1]=0.f; oacc[i][2]=0.f; oacc[i][3]=0.f; }
  float m_[4] = {-INFINITY, -INFINITY, -INFINITY, -INFINITY};
  float l_[4] = {0.f, 0.f, 0.f, 0.f};

  const int ntile = qblk + 1;
  // prologue: stage tile 0 into buf 0
  stage_wave((const char*)(gKs + hbase), (char*)&Ks[0][0], wv, ln);
  stage_wave((const char*)(gVt + hbase), (char*)&Vt[0][0], wv, ln);

  for (int t = 0; t < ntile; ++t) {
    const int cur = t & 1;
    if (t + 1 < ntile) {
      stage_wave((const char*)(gKs + hbase + (size_t)(t + 1) * TILE_SHORTS),
                 (char*)&Ks[cur ^ 1][0], wv, ln);
      stage_wave((const char*)(gVt + hbase + (size_t)(t + 1) * TILE_SHORTS),
                 (char*)&Vt[cur ^ 1][0], wv, ln);
      asm volatile("s_waitcnt vmcnt(8)" ::: "memory");   // tile t done, t+1 in flight
    } else {
      asm volatile("s_waitcnt vmcnt(0)" ::: "memory");
    }
    __builtin_amdgcn_s_barrier();
    __builtin_amdgcn_sched_barrier(0);

    const int kv0 = t * KB;
    // ---- S = Q K^T
    f4 sacc[4];
#pragma unroll
    for (int n = 0; n < 4; ++n) { sacc[n][0]=0.f; sacc[n][1]=0.f; sacc[n][2]=0.f; sacc[n][3]=0.f; }
#pragma unroll
    for (int n = 0; n < 4; ++n)
#pragma unroll
      for (int dt = 0; dt < 4; ++dt) {
        s8 kf = *(const s8*)&Ks[cur][swz(n * 16 + l15, dt * 32 + l4 * 8, DH)];
        sacc[n] = __builtin_amdgcn_mfma_f32_16x16x32_bf16(qf[dt], kf, sacc[n], 0, 0, 0);
      }

    // ---- mask + online softmax
    float pj[4][4];
    float rm[4] = {-INFINITY, -INFINITY, -INFINITY, -INFINITY};
#pragma unroll
    for (int n = 0; n < 4; ++n) {
      int kvcol = kv0 + n * 16 + l15;
#pragma unroll
      for (int j = 0; j < 4; ++j) {
        int qg = qb + wv * 16 + 4 * l4 + j;
        float s = sacc[n][j] * SCALEF;
        if (kvcol > qg) s = -INFINITY;
        pj[n][j] = s;
        rm[j] = fmaxf(rm[j], s);
      }
    }
#pragma unroll
    for (int j = 0; j < 4; ++j) {
      rm[j] = fmaxf(rm[j], __shfl_xor(rm[j], 1, 16));
      rm[j] = fmaxf(rm[j], __shfl_xor(rm[j], 2, 16));
      rm[j] = fmaxf(rm[j], __shfl_xor(rm[j], 4, 16));
      rm[j] = fmaxf(rm[j], __shfl_xor(rm[j], 8, 16));
    }
    float alpha[4], rs[4];
#pragma unroll
    for (int j = 0; j < 4; ++j) {
      float mn = fmaxf(m_[j], rm[j]);
      alpha[j] = __expf(m_[j] - mn);
      m_[j] = mn;
      float s0 = 0.f;
#pragma unroll
      for (int n = 0; n < 4; ++n) {
        float p = __expf(pj[n][j] - mn);
        pj[n][j] = p;
        s0 += p;
      }
      rs[j] = s0;
    }
#pragma unroll
    for (int j = 0; j < 4; ++j) {
      rs[j] += __shfl_xor(rs[j], 1, 16);
      rs[j] += __shfl_xor(rs[j], 2, 16);
      rs[j] += __shfl_xor(rs[j], 4, 16);
      rs[j] += __shfl_xor(rs[j], 8, 16);
      l_[j] = l_[j] * alpha[j] + rs[j];
    }
#pragma unroll
    for (int i = 0; i < 8; ++i)
#pragma unroll
      for (int j = 0; j < 4; ++j) oacc[i][j] *= alpha[j];

    // ---- P -> per-wave LDS tile (wave-local: no barrier needed before PV)
    short* pw = Ps[wv];
#pragma unroll
    for (int n = 0; n < 4; ++n)
#pragma unroll
      for (int j = 0; j < 4; ++j)
        pw[swz(4 * l4 + j, n * 16 + l15, KB)] = f2bf(pj[n][j]);

    s8 pa0 = *(const s8*)&pw[swz(l15, l4 * 8, KB)];
    s8 pa1 = *(const s8*)&pw[swz(l15, 32 + l4 * 8, KB)];
#pragma unroll
    for (int ds = 0; ds < 8; ++ds) {
      s8 vb0 = *(const s8*)&Vt[cur][swz(ds * 16 + l15, l4 * 8, KB)];
      oacc[ds] = __builtin_amdgcn_mfma_f32_16x16x32_bf16(pa0, vb0, oacc[ds], 0, 0, 0);
      s8 vb1 = *(const s8*)&Vt[cur][swz(ds * 16 + l15, 32 + l4 * 8, KB)];
      oacc[ds] = __builtin_amdgcn_mfma_f32_16x16x32_bf16(pa1, vb1, oacc[ds], 0, 0, 0);
    }
    asm volatile("s_waitcnt lgkmcnt(0)" ::: "memory");
    __builtin_amdgcn_s_barrier();
    __builtin_amdgcn_sched_barrier(0);
  }

  // ---- epilogue
#pragma unroll
  for (int j = 0; j < 4; ++j) {
    int qg = qb + wv * 16 + 4 * l4 + j;
    float inv = 1.0f / l_[j];
    float* orow = gO + ((size_t)qg * HN + h) * DH;
#pragma unroll
    for (int ds = 0; ds < 8; ++ds)
      orow[ds * 16 + l15] = oacc[ds][j] * inv;
    if (l15 == 0)
      gT[h * SEQ + qg] = m_[j] + logf(l_[j]) - logf((float)(qg + 1));
  }
}

// ---------------------------------------------------------------- kernel 2
__global__ __launch_bounds__(256, 2) void corm_fwd(
    const float* __restrict__ gK, const short* __restrict__ gQh,
    const short* __restrict__ gQl, const float* __restrict__ gT,
    float* __restrict__ gC)
{
  __shared__ short Qh[2][TILE_SHORTS];   // 32 KB
  __shared__ short Ql[2][TILE_SHORTS];   // 32 KB
  __shared__ float Tt[SEQ];              // 8 KB

  const int kvblk = blockIdx.x, h = blockIdx.y;  // kvblk 0 heaviest, first
  const int kvb = kvblk * KB;
  const int tid = threadIdx.x;
  const int wv = tid >> 6, ln = tid & 63, l15 = ln & 15, l4 = ln >> 4;

  // K rows hi/lo in registers (once per block, from fp32)
  s8 khi[4], klo[4];
  {
    const float* krow = gK + ((size_t)(kvb + wv * 16 + l15) * HN + h) * DH;
#pragma unroll
    for (int dt = 0; dt < 4; ++dt) {
      f4 a = *(const f4*)(krow + dt * 32 + l4 * 8);
      f4 b = *(const f4*)(krow + dt * 32 + l4 * 8 + 4);
#pragma unroll
      for (int e = 0; e < 4; ++e) {
        short hi = f2bf(a[e]); khi[dt][e] = hi; klo[dt][e] = f2bf(a[e] - bf2f(hi));
        short h2 = f2bf(b[e]); khi[dt][4+e] = h2; klo[dt][4+e] = f2bf(b[e] - bf2f(h2));
      }
    }
  }
  // T for q in [kvb, SEQ) into LDS (keeps vmcnt clean inside the pipeline)
  for (int i = tid; i < SEQ - kvb; i += 256) Tt[i] = gT[h * SEQ + kvb + i];
  __syncthreads();

  const size_t hbase = (size_t)h * NBLK * TILE_SHORTS;
  // prologue: stage tile kvblk
  stage_wave((const char*)(gQh + hbase + (size_t)kvblk * TILE_SHORTS),
             (char*)&Qh[kvblk & 1][0], wv, ln);
  stage_wave((const char*)(gQl + hbase + (size_t)kvblk * TILE_SHORTS),
             (char*)&Ql[kvblk & 1][0], wv, ln);

  int fired[4] = {0, 0, 0, 0};
  const int kvrow_mine = kvb + wv * 16 + 4 * l4;  // + j

  for (int t = kvblk; t < NBLK; ++t) {
    const int cur = t & 1;
    if (t + 1 < NBLK) {
      stage_wave((const char*)(gQh + hbase + (size_t)(t + 1) * TILE_SHORTS),
                 (char*)&Qh[cur ^ 1][0], wv, ln);
      stage_wave((const char*)(gQl + hbase + (size_t)(t + 1) * TILE_SHORTS),
                 (char*)&Ql[cur ^ 1][0], wv, ln);
      asm volatile("s_waitcnt vmcnt(8)" ::: "memory");
    } else {
      asm volatile("s_waitcnt vmcnt(0)" ::: "memory");
    }
    __builtin_amdgcn_s_barrier();
    __builtin_amdgcn_sched_barrier(0);

#pragma unroll
    for (int n = 0; n < 4; ++n) {
      f4 acc; acc[0]=0.f; acc[1]=0.f; acc[2]=0.f; acc[3]=0.f;
#pragma unroll
      for (int dt = 0; dt < 4; ++dt) {
        s8 qhb = *(const s8*)&Qh[cur][swz(n * 16 + l15, dt * 32 + l4 * 8, DH)];
        s8 qlb = *(const s8*)&Ql[cur][swz(n * 16 + l15, dt * 32 + l4 * 8, DH)];
        acc = __builtin_amdgcn_mfma_f32_16x16x32_bf16(khi[dt], qhb, acc, 0, 0, 0);
        acc = __builtin_amdgcn_mfma_f32_16x16x32_bf16(khi[dt], qlb, acc, 0, 0, 0);
        acc = __builtin_amdgcn_mfma_f32_16x16x32_bf16(klo[dt], qhb, acc, 0, 0, 0);
      }
      int qg = t * QB + n * 16 + l15;
      float Tq = Tt[qg - kvb];
#pragma unroll
      for (int j = 0; j < 4; ++j) {
        int kvr = kvrow_mine + j;
        if (qg >= kvr && acc[j] * SCALEF >= Tq) fired[j] = 1;
      }
    }
    asm volatile("s_waitcnt lgkmcnt(0)" ::: "memory");
    __builtin_amdgcn_s_barrier();
    __builtin_amdgcn_sched_barrier(0);
  }

#pragma unroll
  for (int j = 0; j < 4; ++j) {
    fired[j] |= __shfl_xor(fired[j], 1, 16);
    fired[j] |= __shfl_xor(fired[j], 2, 16);
    fired[j] |= __shfl_xor(fired[j], 4, 16);
    fired[j] |= __shfl_xor(fired[j], 8, 16);
  }
  if (l15 == 0) {
#pragma unroll
    for (int j = 0; j < 4; ++j)
      gC[h * SEQ + kvrow_mine + j] = fired[j] ? 1.0f : 0.0f;
  }
}

// ---------------------------------------------------------------- launcher
extern "C" void kernel_launch(void* const* d_in, const int* in_sizes, int n_in,
                              void* d_out, int out_size, void* d_ws, size_t ws_size,
                              hipStream_t stream) {
  const float* q = (const float*)d_in[0];
  const float* k = (const float*)d_in[1];
  const float* v = (const float*)d_in[2];
  // d_in[3] = corm_mask: row i is exactly 1/(i+1); folded analytically into T.
  float* out  = (float*)d_out;
  float* corm = out + (size_t)SEQ * HN * DH;

  const size_t ARR = (size_t)HN * NBLK * TILE_SHORTS;  // 8,388,608 shorts / array
  short* Qh = (short*)d_ws;
  short* Ql = Qh + ARR;
  short* Ks = Ql + ARR;
  short* Vt = Ks + ARR;
  float* T  = (float*)(Vt + ARR);   // total ~64.3 MiB of ws

  dim3 blk(256);
  prep_qkv<<<dim3(NBLK, HN), blk, 0, stream>>>(q, k, v, Qh, Ql, Ks, Vt);
  flash_fwd<<<dim3(NBLK, HN), blk, 0, stream>>>(Qh, Ks, Vt, out, T);
  corm_fwd<<<dim3(NBLK, HN), blk, 0, stream>>>(k, Qh, Ql, T, corm);
}

// Round 3
// 223.674 us; speedup vs baseline: 1.7184x; 1.3793x over previous
//
#include <hip/hip_runtime.h>
#include <math.h>

// CORM attention v3, MI355X / gfx950.
// prep : fp32 -> bf16 tile images (exact swizzled LDS layout) for Q(hi,lo), K(hi), V^T
// flash: swapped-QK (kv lane-local softmax), 8 waves/128q, dbuf global_load_lds pipeline
// corm : bf16x3 scores vs T, 8 waves/128kv, dbuf pipeline, 2 blocks/CU.

#define HN   32
#define DH   128
#define SEQ  2048
#define NBLK 32            // SEQ / 64
#define KB   64
#define TILE_SHORTS 8192   // 64 * 128
#define SCALEF 0.08838834764831843f   // 1/sqrt(128)
#define SC2   0.1275174072417346f     // SCALEF * log2(e)
#define LN2   0.6931471805599453f

typedef __attribute__((ext_vector_type(4))) float f4;
typedef __attribute__((ext_vector_type(8))) short s8;

typedef __attribute__((address_space(3))) unsigned lds_u32;
typedef const __attribute__((address_space(1))) unsigned glob_u32;

__device__ __forceinline__ short f2bf(float x) {
  union { float f; unsigned u; } a; a.f = x;
  unsigned r = a.u + 0x7FFFu + ((a.u >> 16) & 1u);  // RNE
  return (short)(r >> 16);
}
__device__ __forceinline__ float bf2f(short h) {
  union { unsigned u; float f; } a;
  a.u = ((unsigned)(unsigned short)h) << 16;
  return a.f;
}
// swizzled short-index in a row-major [R][Cshort] bf16 tile: byte ^= (row&7)<<4
__device__ __forceinline__ int swz(int row, int colShort, int Cshort) {
  int byte = (colShort * 2) ^ ((row & 7) << 4);
  return row * Cshort + (byte >> 1);
}
__device__ __forceinline__ float lanef(float v, int srcLane) {
  return __builtin_bit_cast(float,
      __builtin_amdgcn_ds_bpermute(srcLane * 4, __builtin_bit_cast(int, v)));
}
// 512-thread cooperative stage of one 16KB tile image (2 x 16B per thread)
__device__ __forceinline__ void stage8(const char* g, char* l, int tid) {
  int wb = (tid >> 6) * 2048, lo = (tid & 63) * 16;
  __builtin_amdgcn_global_load_lds((glob_u32*)(g + wb + lo),        (lds_u32*)(l + wb),        16, 0, 0);
  __builtin_amdgcn_global_load_lds((glob_u32*)(g + wb + 1024 + lo), (lds_u32*)(l + wb + 1024), 16, 0, 0);
}

// ---------------------------------------------------------------- prep
__global__ __launch_bounds__(256) void prep_qkv(
    const float* __restrict__ gQ, const float* __restrict__ gK,
    const float* __restrict__ gV, short* __restrict__ oQh,
    short* __restrict__ oQl, short* __restrict__ oKs, short* __restrict__ oVt)
{
  __shared__ short Vs[64][136];
  const int blk = blockIdx.x, h = blockIdx.y, tid = threadIdx.x;
  const size_t toff = ((size_t)h * NBLK + blk) * TILE_SHORTS;

#pragma unroll
  for (int i = 0; i < 4; ++i) {
    int c = tid + 256 * i, r = c >> 4, c0 = (c & 15) * 8;
    size_t rowoff = ((size_t)(blk * 64 + r) * HN + h) * DH + c0;
    {  // Q hi/lo
      f4 a = *(const f4*)(gQ + rowoff), b = *(const f4*)(gQ + rowoff + 4);
      s8 oh, ol;
#pragma unroll
      for (int e = 0; e < 4; ++e) {
        short hi = f2bf(a[e]); oh[e] = hi; ol[e] = f2bf(a[e] - bf2f(hi));
        short h2 = f2bf(b[e]); oh[4+e] = h2; ol[4+e] = f2bf(b[e] - bf2f(h2));
      }
      *(s8*)&oQh[toff + swz(r, c0, DH)] = oh;
      *(s8*)&oQl[toff + swz(r, c0, DH)] = ol;
    }
    {  // K hi
      f4 a = *(const f4*)(gK + rowoff), b = *(const f4*)(gK + rowoff + 4);
      s8 o;
#pragma unroll
      for (int e = 0; e < 4; ++e) { o[e] = f2bf(a[e]); o[4+e] = f2bf(b[e]); }
      *(s8*)&oKs[toff + swz(r, c0, DH)] = o;
    }
    {  // V -> LDS (linear, padded)
      f4 a = *(const f4*)(gV + rowoff), b = *(const f4*)(gV + rowoff + 4);
      s8 o;
#pragma unroll
      for (int e = 0; e < 4; ++e) { o[e] = f2bf(a[e]); o[4+e] = f2bf(b[e]); }
      *(s8*)&Vs[r][c0] = o;
    }
  }
  __syncthreads();
#pragma unroll
  for (int i = 0; i < 4; ++i) {
    int c = tid + 256 * i, d = c >> 3, k0 = (c & 7) * 8;
    s8 o;
#pragma unroll
    for (int j = 0; j < 8; ++j) o[j] = Vs[k0 + j][d];
    *(s8*)&oVt[toff + swz(d, k0, KB)] = o;
  }
}

// ---------------------------------------------------------------- kernel 1
// 8 waves, 128 q-rows per block; swapped QK^T: lane owns q = q0 + l15 for softmax.
__global__ __launch_bounds__(512, 2) void flash_fwd(
    const short* __restrict__ gQh, const short* __restrict__ gKs,
    const short* __restrict__ gVt, float* __restrict__ gO,
    float* __restrict__ gT)
{
  __shared__ short Ks[2][TILE_SHORTS];   // 32 KB
  __shared__ short Vt[2][TILE_SHORTS];   // 32 KB
  __shared__ short Ps[8][16 * KB];       // 16 KB

  const int b = (gridDim.x - 1) - blockIdx.x, h = blockIdx.y;  // heavy first
  const int tid = threadIdx.x;
  const int wv = tid >> 6, ln = tid & 63, l15 = ln & 15, l4 = ln >> 4;
  const int q0 = b * 128 + wv * 16;       // wave's first q row
  const int ntile = 2 * b + 2;
  const size_t hbase = (size_t)h * NBLK * TILE_SHORTS;

  // Q B-frags for this wave's 16 rows (from pre-swizzled global image)
  const short* qtile = gQh + hbase + (size_t)(2 * b + (wv >> 2)) * TILE_SHORTS;
  s8 qf[4];
#pragma unroll
  for (int dt = 0; dt < 4; ++dt)
    qf[dt] = *(const s8*)&qtile[swz((wv & 3) * 16 + l15, dt * 32 + l4 * 8, DH)];

  f4 oacc[8];
#pragma unroll
  for (int i = 0; i < 8; ++i) { oacc[i][0]=0.f; oacc[i][1]=0.f; oacc[i][2]=0.f; oacc[i][3]=0.f; }
  float m1 = -INFINITY, l1 = 0.f;        // per-lane softmax state for q = q0 + l15
  const int abase = (ln & 48) + 4 * l4;  // bpermute src base: lane with l15 = 4*l4+j

  // prologue: tile 0 -> buf 0
  stage8((const char*)(gKs + hbase), (char*)&Ks[0][0], tid);
  stage8((const char*)(gVt + hbase), (char*)&Vt[0][0], tid);

  for (int t = 0; t < ntile; ++t) {
    const int cur = t & 1;
    if (t + 1 < ntile) {
      stage8((const char*)(gKs + hbase + (size_t)(t + 1) * TILE_SHORTS), (char*)&Ks[cur ^ 1][0], tid);
      stage8((const char*)(gVt + hbase + (size_t)(t + 1) * TILE_SHORTS), (char*)&Vt[cur ^ 1][0], tid);
      asm volatile("s_waitcnt vmcnt(4)" ::: "memory");
    } else {
      asm volatile("s_waitcnt vmcnt(0)" ::: "memory");
    }
    __builtin_amdgcn_s_barrier();
    __builtin_amdgcn_sched_barrier(0);

    if (t * 64 <= q0 + 15) {  // wave has unmasked rows in this tile
      // ---- S^T = K Q^T : D[kv = n*16+4*l4+j][q = l15]
      f4 sacc[4];
#pragma unroll
      for (int n = 0; n < 4; ++n) { sacc[n][0]=0.f; sacc[n][1]=0.f; sacc[n][2]=0.f; sacc[n][3]=0.f; }
#pragma unroll
      for (int n = 0; n < 4; ++n)
#pragma unroll
        for (int dt = 0; dt < 4; ++dt) {
          s8 kf = *(const s8*)&Ks[cur][swz(n * 16 + l15, dt * 32 + l4 * 8, DH)];
          sacc[n] = __builtin_amdgcn_mfma_f32_16x16x32_bf16(kf, qf[dt], sacc[n], 0, 0, 0);
        }

      // ---- log2-domain scores + mask (diagonal tiles only)
      float z[4][4];
      const bool needmask = (t * 64 + 63 > q0);
      if (needmask) {
#pragma unroll
        for (int n = 0; n < 4; ++n)
#pragma unroll
          for (int j = 0; j < 4; ++j) {
            int kv = t * 64 + n * 16 + 4 * l4 + j;
            float v = sacc[n][j] * SC2;
            z[n][j] = (kv > q0 + l15) ? -INFINITY : v;
          }
      } else {
#pragma unroll
        for (int n = 0; n < 4; ++n)
#pragma unroll
          for (int j = 0; j < 4; ++j) z[n][j] = sacc[n][j] * SC2;
      }

      // ---- row max: in-lane tree + 2 cross-lane ops
      float mn4[4];
#pragma unroll
      for (int n = 0; n < 4; ++n)
        mn4[n] = fmaxf(fmaxf(z[n][0], z[n][1]), fmaxf(z[n][2], z[n][3]));
      float mt = fmaxf(fmaxf(mn4[0], mn4[1]), fmaxf(mn4[2], mn4[3]));
      mt = fmaxf(mt, __shfl_xor(mt, 16));
      mt = fmaxf(mt, __shfl_xor(mt, 32));

      float mn = fmaxf(m1, mt);
      float alpha = exp2f(m1 - mn);   // m1=-inf at t=0 -> alpha=0, never NaN
      m1 = mn;
      float sn4[4];
#pragma unroll
      for (int n = 0; n < 4; ++n) {
#pragma unroll
        for (int j = 0; j < 4; ++j) z[n][j] = exp2f(z[n][j] - mn);
        sn4[n] = (z[n][0] + z[n][1]) + (z[n][2] + z[n][3]);
      }
      float rs = (sn4[0] + sn4[1]) + (sn4[2] + sn4[3]);
      rs += __shfl_xor(rs, 16);
      rs += __shfl_xor(rs, 32);
      l1 = l1 * alpha + rs;

      // ---- alpha for the PV accumulator layout (rows q = 4*l4+j)
      float aj[4];
#pragma unroll
      for (int j = 0; j < 4; ++j) aj[j] = lanef(alpha, abase + j);
#pragma unroll
      for (int ds = 0; ds < 8; ++ds)
#pragma unroll
        for (int j = 0; j < 4; ++j) oacc[ds][j] *= aj[j];

      // ---- P -> wave-local LDS tile [q=l15][kv], packed b64 writes
      short* pw = Ps[wv];
#pragma unroll
      for (int n = 0; n < 4; ++n) {
        unsigned lo, hi;
        asm("v_cvt_pk_bf16_f32 %0, %1, %2" : "=v"(lo) : "v"(z[n][0]), "v"(z[n][1]));
        asm("v_cvt_pk_bf16_f32 %0, %1, %2" : "=v"(hi) : "v"(z[n][2]), "v"(z[n][3]));
        uint2 w; w.x = lo; w.y = hi;
        *(uint2*)&pw[swz(l15, n * 16 + 4 * l4, KB)] = w;
      }

      // ---- PV: oacc[q=4*l4+j][d=ds*16+l15] += P * V
      s8 pa0 = *(const s8*)&pw[swz(l15, l4 * 8, KB)];
      s8 pa1 = *(const s8*)&pw[swz(l15, 32 + l4 * 8, KB)];
#pragma unroll
      for (int ds = 0; ds < 8; ++ds) {
        s8 vb0 = *(const s8*)&Vt[cur][swz(ds * 16 + l15, l4 * 8, KB)];
        oacc[ds] = __builtin_amdgcn_mfma_f32_16x16x32_bf16(pa0, vb0, oacc[ds], 0, 0, 0);
        s8 vb1 = *(const s8*)&Vt[cur][swz(ds * 16 + l15, 32 + l4 * 8, KB)];
        oacc[ds] = __builtin_amdgcn_mfma_f32_16x16x32_bf16(pa1, vb1, oacc[ds], 0, 0, 0);
      }
    }
    asm volatile("s_waitcnt lgkmcnt(0)" ::: "memory");
    __builtin_amdgcn_s_barrier();
    __builtin_amdgcn_sched_barrier(0);
  }

  // ---- epilogue
  float linv = 1.0f / l1;
  float lj[4];
#pragma unroll
  for (int j = 0; j < 4; ++j) lj[j] = lanef(linv, abase + j);
#pragma unroll
  for (int j = 0; j < 4; ++j) {
    int qg = q0 + 4 * l4 + j;
    float* orow = gO + ((size_t)qg * HN + h) * DH;
#pragma unroll
    for (int ds = 0; ds < 8; ++ds)
      orow[ds * 16 + l15] = oacc[ds][j] * lj[j];
  }
  if (l4 == 0) {
    int qg = q0 + l15;
    gT[h * SEQ + qg] = LN2 * (m1 + log2f(l1)) - logf((float)(qg + 1));
  }
}

// ---------------------------------------------------------------- kernel 2
// 8 waves, 128 kv-rows per block; K rows hi/lo in regs; Q(hi,lo) tiles dbuf'd.
__global__ __launch_bounds__(512, 4) void corm_fwd(
    const float* __restrict__ gK, const short* __restrict__ gQh,
    const short* __restrict__ gQl, const float* __restrict__ gT,
    float* __restrict__ gC)
{
  __shared__ short Qh[2][TILE_SHORTS];   // 32 KB
  __shared__ short Ql[2][TILE_SHORTS];   // 32 KB
  __shared__ float Tt[SEQ];              // 8 KB

  const int b = blockIdx.x, h = blockIdx.y;   // b=0 heaviest, first
  const int kv0 = b * 128;
  const int tid = threadIdx.x;
  const int wv = tid >> 6, ln = tid & 63, l15 = ln & 15, l4 = ln >> 4;

  // this wave's 16 K rows as hi/lo A-frags
  s8 khi[4], klo[4];
  {
    const float* krow = gK + ((size_t)(kv0 + wv * 16 + l15) * HN + h) * DH;
#pragma unroll
    for (int dt = 0; dt < 4; ++dt) {
      f4 a = *(const f4*)(krow + dt * 32 + l4 * 8);
      f4 bb = *(const f4*)(krow + dt * 32 + l4 * 8 + 4);
#pragma unroll
      for (int e = 0; e < 4; ++e) {
        short hi = f2bf(a[e]); khi[dt][e] = hi; klo[dt][e] = f2bf(a[e] - bf2f(hi));
        short h2 = f2bf(bb[e]); khi[dt][4+e] = h2; klo[dt][4+e] = f2bf(bb[e] - bf2f(h2));
      }
    }
  }
  for (int i = tid; i < SEQ - kv0; i += 512) Tt[i] = gT[h * SEQ + kv0 + i];
  __syncthreads();

  const size_t hbase = (size_t)h * NBLK * TILE_SHORTS;
  const int t0 = 2 * b;
  stage8((const char*)(gQh + hbase + (size_t)t0 * TILE_SHORTS), (char*)&Qh[t0 & 1][0], tid);
  stage8((const char*)(gQl + hbase + (size_t)t0 * TILE_SHORTS), (char*)&Ql[t0 & 1][0], tid);

  int fired[4] = {0, 0, 0, 0};
  const int kvrow_mine = kv0 + wv * 16 + 4 * l4;  // + j

  for (int t = t0; t < NBLK; ++t) {
    const int cur = t & 1;
    if (t + 1 < NBLK) {
      stage8((const char*)(gQh + hbase + (size_t)(t + 1) * TILE_SHORTS), (char*)&Qh[cur ^ 1][0], tid);
      stage8((const char*)(gQl + hbase + (size_t)(t + 1) * TILE_SHORTS), (char*)&Ql[cur ^ 1][0], tid);
      asm volatile("s_waitcnt vmcnt(4)" ::: "memory");
    } else {
      asm volatile("s_waitcnt vmcnt(0)" ::: "memory");
    }
    __builtin_amdgcn_s_barrier();
    __builtin_amdgcn_sched_barrier(0);

    if (kv0 + wv * 16 <= t * 64 + 63) {  // some q >= wave's kv rows
#pragma unroll
      for (int n = 0; n < 4; ++n) {
        f4 acc; acc[0]=0.f; acc[1]=0.f; acc[2]=0.f; acc[3]=0.f;
#pragma unroll
        for (int dt = 0; dt < 4; ++dt) {
          s8 qhb = *(const s8*)&Qh[cur][swz(n * 16 + l15, dt * 32 + l4 * 8, DH)];
          s8 qlb = *(const s8*)&Ql[cur][swz(n * 16 + l15, dt * 32 + l4 * 8, DH)];
          acc = __builtin_amdgcn_mfma_f32_16x16x32_bf16(khi[dt], qhb, acc, 0, 0, 0);
          acc = __builtin_amdgcn_mfma_f32_16x16x32_bf16(khi[dt], qlb, acc, 0, 0, 0);
          acc = __builtin_amdgcn_mfma_f32_16x16x32_bf16(klo[dt], qhb, acc, 0, 0, 0);
        }
        int qg = t * 64 + n * 16 + l15;
        float Tq = Tt[qg - kv0];
#pragma unroll
        for (int j = 0; j < 4; ++j) {
          int kvr = kvrow_mine + j;
          if (qg >= kvr && acc[j] * SCALEF >= Tq) fired[j] = 1;
        }
      }
    }
    asm volatile("s_waitcnt lgkmcnt(0)" ::: "memory");
    __builtin_amdgcn_s_barrier();
    __builtin_amdgcn_sched_barrier(0);
  }

#pragma unroll
  for (int j = 0; j < 4; ++j) {
    fired[j] |= __shfl_xor(fired[j], 1, 16);
    fired[j] |= __shfl_xor(fired[j], 2, 16);
    fired[j] |= __shfl_xor(fired[j], 4, 16);
    fired[j] |= __shfl_xor(fired[j], 8, 16);
  }
  if (l15 == 0) {
#pragma unroll
    for (int j = 0; j < 4; ++j)
      gC[h * SEQ + kvrow_mine + j] = fired[j] ? 1.0f : 0.0f;
  }
}

// ---------------------------------------------------------------- launcher
extern "C" void kernel_launch(void* const* d_in, const int* in_sizes, int n_in,
                              void* d_out, int out_size, void* d_ws, size_t ws_size,
                              hipStream_t stream) {
  const float* q = (const float*)d_in[0];
  const float* k = (const float*)d_in[1];
  const float* v = (const float*)d_in[2];
  // d_in[3] = corm_mask: row i is exactly 1/(i+1); folded analytically into T.
  float* out  = (float*)d_out;
  float* corm = out + (size_t)SEQ * HN * DH;

  const size_t ARR = (size_t)HN * NBLK * TILE_SHORTS;  // 8,388,608 shorts / array
  short* Qh = (short*)d_ws;
  short* Ql = Qh + ARR;
  short* Ks = Ql + ARR;
  short* Vt = Ks + ARR;
  float* T  = (float*)(Vt + ARR);   // total ~64.3 MiB of ws

  prep_qkv<<<dim3(NBLK, HN), dim3(256), 0, stream>>>(q, k, v, Qh, Ql, Ks, Vt);
  flash_fwd<<<dim3(16, HN), dim3(512), 0, stream>>>(Qh, Ks, Vt, out, T);
  corm_fwd<<<dim3(16, HN), dim3(512), 0, stream>>>(k, Qh, Ql, T, corm);
}